// Round 1
// baseline (2505.113 us; speedup 1.0000x reference)
//
#include <hip/hip_runtime.h>

#define IC 256
#define OCN 128
#define NBATCH 8
#define XD 16
#define YTOT 35937          // total y points per (n,oc) across 8 parity classes
#define WR_FLOATS 884736    // 27 * 256 * 128
#define ICB 8

// class c = ez*4 + ey*2 + ex ; dz = 17-ez, dy = 17-ey, dx = 17-ex ; taps per axis = 2-e
__device__ __forceinline__ int class_yoff(int c){
  int ez=c>>2, ey=(c>>1)&1, ex=c&1;
  return ez ? (ey ? (ex?31841:27489) : (ex?23137:18513))
            : (ey ? (ex?14161: 9537) : (ex? 4913:    0));
}
__device__ __forceinline__ int class_woff27(int c){
  int ez=c>>2, ey=(c>>1)&1, ex=c&1;
  return ez ? (ey ? (ex?26:24) : (ex?22:18))
            : (ey ? (ex?16:12) : (ex? 8: 0));
}

// ---------------- weight reorg: w[oc][ic][3][3][3] -> wr[tap27][ic][oc] ----------------
__global__ __launch_bounds__(256) void reorg_w(const float* __restrict__ w, float* __restrict__ wr){
  int idx = blockIdx.x*256 + threadIdx.x;
  if (idx >= WR_FLOATS) return;
  int oc = idx & 127;
  int ic = (idx >> 7) & 255;
  int tt = idx >> 15;           // 0..26 global tap id
  const int toffs[8] = {0,8,12,16,18,22,24,26};
  const int tcnt[8]  = {8,4,4,2,4,2,2,1};
  int c=0, t=0;
  #pragma unroll
  for (int cc=0; cc<8; ++cc){
    if (tt >= toffs[cc] && tt < toffs[cc]+tcnt[cc]){ c=cc; t=tt-toffs[cc]; }
  }
  int ez=c>>2, ey=(c>>1)&1, ex=c&1;
  int ty=2-ey, tx=2-ex;
  int ax = t % tx; int ay = (t/tx)%ty; int az = t/(tx*ty);
  int qz = ez?1:(az?2:0), qy = ey?1:(ay?2:0), qx = ex?1:(ax?2:0);
  wr[idx] = w[(size_t)(oc*IC + ic)*27 + (qz*3+qy)*3+qx];
}

// ---------------- stage 1: per-class dense conv (the transposed conv) ----------------
// grid: (132 = sum dz over classes, ocChunk/32, nChunk) ; block 256
__global__ __launch_bounds__(256) void stage1(const float* __restrict__ x, const float* __restrict__ wr,
                                              float* __restrict__ y, int n0, int oc0, int ocChunk){
  __shared__ float xs[ICB][2][18][18];
  __shared__ float wls[ICB][8][32];
  const int tid = threadIdx.x;
  int bz = blockIdx.x;
  int c, mz;
  if (bz < 68){ c = bz/17; mz = bz - c*17; }
  else        { int b2 = bz-68; c = 4 + (b2>>4); mz = b2 & 15; }
  const int ez=c>>2, ey=(c>>1)&1, ex=c&1;
  const int tz=2-ez, ty=2-ey, tx=2-ex;
  const int dy=17-ey, dx=17-ex;
  const int Nxy = dy*dx;
  const int ptl = tid & 63, ocl = tid >> 6;   // 64 point-lanes x 4 oc-lanes
  const int nl = blockIdx.z, ocg = blockIdx.y;

  int offk[5]; bool kv[5];
  #pragma unroll
  for (int k=0;k<5;++k){
    int p = ptl + 64*k;
    bool v = p < Nxy;
    int pp = v ? p : 0;
    int my = pp / dx, mx = pp - my*dx;
    offk[k] = (my+ey)*18 + (mx+ex);
    kv[k] = v;
  }

  float acc[8][5];
  #pragma unroll
  for (int j=0;j<8;++j)
    #pragma unroll
    for (int k=0;k<5;++k) acc[j][k]=0.f;

  const float* xbase = x + (size_t)(n0+nl)*IC*4096;
  const int w27 = class_woff27(c);
  const int t = tz*ty*tx;
  const int sPerIc = tz*324;

  for (int ic0=0; ic0<IC; ic0+=ICB){
    // stage x tile (tz z-planes, 18x18 zero-padded xy) into LDS
    int xslots = ICB*sPerIc;
    for (int s=tid; s<xslots; s+=256){
      int ic = s / sPerIc; int r = s - ic*sPerIc;
      int az = r / 324;    int r2 = r - az*324;
      int yy = r2 / 18, xx = r2 - yy*18;
      int zc = ez ? mz : (mz-1+az);
      int yc = yy-1, xc = xx-1;
      float v = 0.f;
      if ((unsigned)zc < 16u && (unsigned)yc < 16u && (unsigned)xc < 16u)
        v = xbase[(size_t)(ic0+ic)*4096 + zc*256 + yc*16 + xc];
      xs[ic][az][yy][xx] = v;
    }
    // stage weights [ic][tap][32 oc]
    int wslots = ICB*t*32;
    for (int s=tid; s<wslots; s+=256){
      int ic = s/(t*32); int r = s - ic*(t*32);
      int tt = r >> 5; int oo = r & 31;
      wls[ic][tt][oo] = wr[((size_t)(w27+tt)*IC + (ic0+ic))*OCN + (oc0 + ocg*32 + oo)];
    }
    __syncthreads();

    #pragma unroll 1
    for (int ic=0; ic<ICB; ++ic){
      for (int az=0; az<tz; ++az){
        for (int ay=0; ay<ty; ++ay){
          for (int ax=0; ax<tx; ++ax){
            int tt = (az*ty+ay)*tx+ax;
            const float4 wA = *(const float4*)&wls[ic][tt][ocl*8];
            const float4 wB = *(const float4*)&wls[ic][tt][ocl*8+4];
            const float* xp = &xs[ic][az][ay][ax];
            #pragma unroll
            for (int k=0;k<5;++k){
              float xv = xp[offk[k]];
              acc[0][k] += wA.x*xv; acc[1][k] += wA.y*xv;
              acc[2][k] += wA.z*xv; acc[3][k] += wA.w*xv;
              acc[4][k] += wB.x*xv; acc[5][k] += wB.y*xv;
              acc[6][k] += wB.z*xv; acc[7][k] += wB.w*xv;
            }
          }
        }
      }
    }
    __syncthreads();
  }

  const int ybase_cls = class_yoff(c) + mz*Nxy;
  #pragma unroll
  for (int oj=0;oj<8;++oj){
    int oc_local = ocg*32 + ocl*8 + oj;
    float* yp = y + (size_t)(nl*ocChunk + oc_local)*YTOT + ybase_cls;
    #pragma unroll
    for (int k=0;k<5;++k){
      int p = ptl + 64*k;
      if (kv[k]) yp[p] = acc[oj][k];
    }
  }
}

// ---------------- stage 2: separable FIR ([.25 .75 .75 .25] per axis) + bias ----------------
// grid: (8 z-groups, ocChunk, nChunk) ; block 256
__global__ __launch_bounds__(256) void stage2(const float* __restrict__ y, const float* __restrict__ bias,
                                              float* __restrict__ out, int n0, int oc0, int ocChunk){
  __shared__ float ys[7][35][36];
  __shared__ float t1[35][36];
  __shared__ float t2[32][36];
  const int tid = threadIdx.x;
  const int zg = blockIdx.x;
  const int ocl = blockIdx.y;
  const int nl  = blockIdx.z;
  const float* yp = y + (size_t)(nl*ocChunk + ocl)*YTOT;

  for (int s=tid; s<7*1225; s+=256){
    int pl = s/1225; int r = s - pl*1225;
    int uyi = r/35, uxi = r - uyi*35;
    int uz = zg*4 - 1 + pl;
    int uy = uyi - 1, ux = uxi - 1;
    float v = 0.f;
    if ((unsigned)uz < 33u && (unsigned)uy < 33u && (unsigned)ux < 33u){
      int cz=uz&1, cy=uy&1, cx=ux&1;
      int cc = cz*4 + cy*2 + cx;
      int dy = 17-cy, dx = 17-cx;
      v = yp[class_yoff(cc) + ((uz>>1)*dy + (uy>>1))*dx + (ux>>1)];
    }
    ys[pl][uyi][uxi] = v;
  }
  __syncthreads();

  const float b = bias[oc0 + ocl];
  for (int mz=0; mz<4; ++mz){
    for (int s=tid; s<1225; s+=256){
      int uyi = s/35, uxi = s - uyi*35;
      t1[uyi][uxi] = 0.25f*ys[mz  ][uyi][uxi] + 0.75f*ys[mz+1][uyi][uxi]
                   + 0.75f*ys[mz+2][uyi][uxi] + 0.25f*ys[mz+3][uyi][uxi];
    }
    __syncthreads();
    for (int s=tid; s<32*35; s+=256){
      int oy = s/35, uxi = s - oy*35;
      t2[oy][uxi] = 0.25f*t1[oy][uxi] + 0.75f*t1[oy+1][uxi]
                  + 0.75f*t1[oy+2][uxi] + 0.25f*t1[oy+3][uxi];
    }
    __syncthreads();
    int oz = zg*4 + mz;
    float* op = out + ((size_t)((n0+nl)*OCN + (oc0+ocl))*32 + oz)*1024;
    for (int s=tid; s<1024; s+=256){
      int oy = s>>5, ox = s&31;
      op[s] = 0.25f*t2[oy][ox] + 0.75f*t2[oy][ox+1]
            + 0.75f*t2[oy][ox+2] + 0.25f*t2[oy][ox+3] + b;
    }
    __syncthreads();
  }
}

extern "C" void kernel_launch(void* const* d_in, const int* in_sizes, int n_in,
                              void* d_out, int out_size, void* d_ws, size_t ws_size,
                              hipStream_t stream) {
  const float* x    = (const float*)d_in[0];
  const float* w    = (const float*)d_in[1];
  const float* bias = (const float*)d_in[2];
  float* out = (float*)d_out;
  float* wr  = (float*)d_ws;
  float* yb  = wr + WR_FLOATS;

  size_t avail = ws_size > (size_t)WR_FLOATS*4 ? ws_size - (size_t)WR_FLOATS*4 : 0;
  int nChunk, ocChunk;
  if      (avail >= (size_t)8*128*YTOT*4) { nChunk=8; ocChunk=128; }
  else if (avail >= (size_t)128*YTOT*4)   { nChunk=1; ocChunk=128; }
  else                                    { nChunk=1; ocChunk=32;  }

  reorg_w<<<dim3(WR_FLOATS/256), 256, 0, stream>>>(w, wr);

  for (int n0=0; n0<NBATCH; n0+=nChunk){
    for (int oc0=0; oc0<OCN; oc0+=ocChunk){
      stage1<<<dim3(132, ocChunk/32, nChunk), 256, 0, stream>>>(x, wr, yb, n0, oc0, ocChunk);
      stage2<<<dim3(8, ocChunk, nChunk), 256, 0, stream>>>(yb, bias, out, n0, oc0, ocChunk);
    }
  }
}

// Round 2
// 934.206 us; speedup vs baseline: 2.6815x; 2.6815x over previous
//
#include <hip/hip_runtime.h>

typedef __attribute__((ext_vector_type(4))) float f32x4;
typedef __attribute__((ext_vector_type(8))) short s16x8;
typedef unsigned short u16;
typedef unsigned int   u32;

#define NBATCH 8
#define ICN 256
#define OCN 128
#define YTOT 35937
#define WRE 884736          // 27*128*256
#define XTE 8388608         // 8*256*4096

__host__ __device__ constexpr int cls_yoff(int c){
  return (c==0)?0:(c==1)?4913:(c==2)?9537:(c==3)?14161:
         (c==4)?18513:(c==5)?23137:(c==6)?27489:31841;
}

__device__ __forceinline__ u16 f2bf(float v){
  u32 u = __float_as_uint(v);
  u32 r = u + 0x7FFFu + ((u>>16)&1u);
  return (u16)(r>>16);
}
__device__ __forceinline__ float bf2f(u16 b){ return __uint_as_float(((u32)b)<<16); }

// ---------------- prep_w: w[oc][ic][27] fp32 -> wh/wl[tap27][oc][ic] bf16 hi/lo ----------------
__global__ __launch_bounds__(256) void prep_w(const float* __restrict__ w,
                                              u16* __restrict__ wh, u16* __restrict__ wl){
  int idx = blockIdx.x*256 + threadIdx.x;
  if (idx >= WRE) return;
  int ic = idx & 255, oc = (idx>>8)&127, tt = idx>>15;
  const int toffs[8] = {0,8,12,16,18,22,24,26};
  const int tcnt[8]  = {8,4,4,2,4,2,2,1};
  int c=0, t=0;
  #pragma unroll
  for (int cc=0; cc<8; ++cc)
    if (tt>=toffs[cc] && tt<toffs[cc]+tcnt[cc]){ c=cc; t=tt-toffs[cc]; }
  int ez=c>>2, ey=(c>>1)&1, ex=c&1;
  int ty=2-ey, tx=2-ex;
  int ax=t%tx, ay=(t/tx)%ty, az=t/(tx*ty);
  int qz = ez?1:(az?2:0), qy = ey?1:(ay?2:0), qx = ex?1:(ax?2:0);
  float v = w[((size_t)oc*ICN + ic)*27 + (qz*3+qy)*3+qx];
  u16 h = f2bf(v);
  wh[idx] = h;
  wl[idx] = f2bf(v - bf2f(h));
}

// ---------------- prep_x: x[n][ic][4096] fp32 -> xh/xl[n][icc8][4096][32ic] bf16 hi/lo ----------------
__global__ __launch_bounds__(256) void prep_x(const float* __restrict__ x,
                                              u16* __restrict__ xh, u16* __restrict__ xl){
  u32 o = blockIdx.x*256 + threadIdx.x;   // < 8388608 exactly
  int il = o & 31, p = (o>>5)&4095, icc = (o>>17)&7, n = o>>20;
  float v = x[(size_t)(n*256 + icc*32 + il)*4096 + p];
  u16 h = f2bf(v);
  xh[o] = h;
  xl[o] = f2bf(v - bf2f(h));
}

// ---------------- stage 1: per-class dense conv via split-bf16 MFMA ----------------
// grid: (ceil(NXY/64), DZ, nChunk), block 128 (2 waves, each 64M x 64oc)
template<int EZ,int EY,int EX>
__global__ __launch_bounds__(128) void stage1(const u16* __restrict__ xh, const u16* __restrict__ xl,
                                              const u16* __restrict__ wh, const u16* __restrict__ wl,
                                              float* __restrict__ y, int n0)
{
  constexpr int TZ=2-EZ, TY=2-EY, TX=2-EX;
  constexpr int DZ=17-EZ, DY=17-EY, DX=17-EX, NXY=DY*DX;
  constexpr int CLS = EZ*4+EY*2+EX;
  constexpr int W27 = (CLS==0)?0:(CLS==1)?8:(CLS==2)?12:(CLS==3)?16:
                      (CLS==4)?18:(CLS==5)?22:(CLS==6)?24:26;
  constexpr int YOFF = cls_yoff(CLS);
  constexpr int AST  = 40;                // ushorts per staged position (32 ic + 8 pad)
  constexpr int APOS = TZ*6*17;           // staged positions
  constexpr int AHALF= APOS*AST;          // hi block (ushorts)
  constexpr int BHALF= 128*40;
  constexpr int POOLU = 2*AHALF + 2*BHALF;
  constexpr int POOLB = (POOLU*2 > 33280) ? POOLU*2 : 33280;   // union w/ 2x64x65 f32 transpose
  __shared__ __align__(16) char pool[POOLB];
  u16* As = (u16*)pool;
  u16* Bs = As + 2*AHALF;

  const int tid = threadIdx.x;
  const int wv  = tid>>6, ln = tid&63;
  const int mt = blockIdx.x, mz = blockIdx.y, nl = blockIdx.z;
  const int my0 = (mt*64)/DX;

  int posA[4];
  #pragma unroll
  for (int fi=0; fi<4; ++fi){
    int m = mt*64 + fi*16 + (ln&15);
    if (m > NXY-1) m = NXY-1;             // clamp padding rows (stores guarded)
    int my = m/DX, mx = m - my*DX;
    posA[fi] = ((my - my0)*17 + mx)*AST + (ln>>4)*8;
  }
  int posB[4];
  #pragma unroll
  for (int fj=0; fj<4; ++fj)
    posB[fj] = (wv*64 + fj*16 + (ln&15))*40 + (ln>>4)*8;

  f32x4 acc[4][4];
  #pragma unroll
  for (int i=0;i<4;++i)
    #pragma unroll
    for (int j=0;j<4;++j) acc[i][j] = (f32x4){0.f,0.f,0.f,0.f};

  const size_t nbase = (size_t)(n0+nl)*(ICN*4096);

  #pragma unroll 1
  for (int icc=0; icc<8; ++icc){
    // ---- stage A tile (hi+lo), footprint TZ x 6rows x 17x x 32ic ----
    #pragma unroll 1
    for (int s=tid; s<APOS*4; s+=128){
      int icg = s & 3;
      int pos = s >> 2;
      int xi  = pos % 17;
      int rem = pos / 17;
      int yi  = rem % 6;
      int az  = rem / 6;
      int zc = EZ ? mz : (mz-1+az);
      int yc = my0 + yi + (EY-1);
      int xc = xi + (EX-1);
      uint4 vh = {0,0,0,0}, vl = {0,0,0,0};
      if ((u32)zc<16u && (u32)yc<16u && (u32)xc<16u){
        size_t g = nbase + (size_t)icc*131072 + (size_t)((zc*256+yc*16+xc)*32 + icg*8);
        vh = *(const uint4*)(xh + g);
        vl = *(const uint4*)(xl + g);
      }
      *(uint4*)&As[pos*AST + icg*8]         = vh;
      *(uint4*)&As[AHALF + pos*AST + icg*8] = vl;
    }
    // ---- taps (fully unrolled) ----
    #pragma unroll
    for (int az=0; az<TZ; ++az)
    #pragma unroll
    for (int ay=0; ay<TY; ++ay)
    #pragma unroll
    for (int ax=0; ax<TX; ++ax){
      const int t = (az*TY+ay)*TX+ax;
      // stage B[tap]: 128oc x 32ic, hi+lo
      #pragma unroll 1
      for (int s=tid; s<1024; s+=128){
        int icg = s & 3; int oc = (s>>2)&127; int hl = s>>9;
        const u16* src = (hl? wl : wh) + (((size_t)(W27+t)*128 + oc)*256 + icc*32 + icg*8);
        *(uint4*)&Bs[hl*BHALF + oc*40 + icg*8] = *(const uint4*)src;
      }
      __syncthreads();
      const int toff = ((az*6+ay)*17+ax)*AST;
      s16x8 ahf[4], alf[4], bhf[4], blf[4];
      #pragma unroll
      for (int fi=0; fi<4; ++fi){
        ahf[fi] = *(const s16x8*)&As[posA[fi]+toff];
        alf[fi] = *(const s16x8*)&As[AHALF+posA[fi]+toff];
      }
      #pragma unroll
      for (int fj=0; fj<4; ++fj){
        bhf[fj] = *(const s16x8*)&Bs[posB[fj]];
        blf[fj] = *(const s16x8*)&Bs[BHALF+posB[fj]];
      }
      #pragma unroll
      for (int fi=0; fi<4; ++fi)
      #pragma unroll
      for (int fj=0; fj<4; ++fj){
        acc[fi][fj] = __builtin_amdgcn_mfma_f32_16x16x32_bf16(ahf[fi], bhf[fj], acc[fi][fj],0,0,0);
        acc[fi][fj] = __builtin_amdgcn_mfma_f32_16x16x32_bf16(ahf[fi], blf[fj], acc[fi][fj],0,0,0);
        acc[fi][fj] = __builtin_amdgcn_mfma_f32_16x16x32_bf16(alf[fi], bhf[fj], acc[fi][fj],0,0,0);
      }
      __syncthreads();
    }
  }

  // ---- epilogue: transpose 64x64 per wave through LDS, coalesced store ----
  float* tr = (float*)pool + wv*(64*65);
  #pragma unroll
  for (int fi=0; fi<4; ++fi)
  #pragma unroll
  for (int fj=0; fj<4; ++fj)
  #pragma unroll
  for (int j=0; j<4; ++j)
    tr[(fj*16 + (ln&15))*65 + fi*16 + (ln>>4)*4 + j] = acc[fi][fj][j];
  __syncthreads();
  const int mrem = NXY - mt*64;
  float* ybp = y + YOFF + mz*NXY + mt*64;
  for (int oc=0; oc<64; ++oc){
    float v = tr[oc*65 + ln];
    if (ln < mrem)
      ybp[(size_t)(nl*128 + wv*64 + oc)*YTOT + ln] = v;
  }
}

// ---------------- stage 2: separable FIR ([.25 .75 .75 .25] per axis) + bias ----------------
__device__ __forceinline__ int class_yoff_d(int c){ return cls_yoff(c); }

__global__ __launch_bounds__(256) void stage2(const float* __restrict__ y, const float* __restrict__ bias,
                                              float* __restrict__ out, int n0, int oc0, int ocChunk){
  __shared__ float ys[7][35][36];
  __shared__ float t1[35][36];
  __shared__ float t2[32][36];
  const int tid = threadIdx.x;
  const int zg = blockIdx.x;
  const int ocl = blockIdx.y;
  const int nl  = blockIdx.z;
  const float* yp = y + (size_t)(nl*ocChunk + ocl)*YTOT;

  for (int s=tid; s<7*1225; s+=256){
    int pl = s/1225; int r = s - pl*1225;
    int uyi = r/35, uxi = r - uyi*35;
    int uz = zg*4 - 1 + pl;
    int uy = uyi - 1, ux = uxi - 1;
    float v = 0.f;
    if ((unsigned)uz < 33u && (unsigned)uy < 33u && (unsigned)ux < 33u){
      int cz=uz&1, cy=uy&1, cx=ux&1;
      int cc = cz*4 + cy*2 + cx;
      int dy = 17-cy, dx = 17-cx;
      v = yp[class_yoff_d(cc) + ((uz>>1)*dy + (uy>>1))*dx + (ux>>1)];
    }
    ys[pl][uyi][uxi] = v;
  }
  __syncthreads();

  const float b = bias[oc0 + ocl];
  for (int mz=0; mz<4; ++mz){
    for (int s=tid; s<1225; s+=256){
      int uyi = s/35, uxi = s - uyi*35;
      t1[uyi][uxi] = 0.25f*ys[mz  ][uyi][uxi] + 0.75f*ys[mz+1][uyi][uxi]
                   + 0.75f*ys[mz+2][uyi][uxi] + 0.25f*ys[mz+3][uyi][uxi];
    }
    __syncthreads();
    for (int s=tid; s<32*35; s+=256){
      int oy = s/35, uxi = s - oy*35;
      t2[oy][uxi] = 0.25f*t1[oy][uxi] + 0.75f*t1[oy+1][uxi]
                  + 0.75f*t1[oy+2][uxi] + 0.25f*t1[oy+3][uxi];
    }
    __syncthreads();
    int oz = zg*4 + mz;
    float* op = out + ((size_t)((n0+nl)*OCN + (oc0+ocl))*32 + oz)*1024;
    for (int s=tid; s<1024; s+=256){
      int oy = s>>5, ox = s&31;
      op[s] = 0.25f*t2[oy][ox] + 0.75f*t2[oy][ox+1]
            + 0.75f*t2[oy][ox+2] + 0.25f*t2[oy][ox+3] + b;
    }
    __syncthreads();
  }
}

extern "C" void kernel_launch(void* const* d_in, const int* in_sizes, int n_in,
                              void* d_out, int out_size, void* d_ws, size_t ws_size,
                              hipStream_t stream) {
  const float* x    = (const float*)d_in[0];
  const float* w    = (const float*)d_in[1];
  const float* bias = (const float*)d_in[2];
  float* out = (float*)d_out;

  u16* wh = (u16*)d_ws;
  u16* wl = wh + WRE;
  u16* xh = wl + WRE;
  u16* xl = xh + XTE;
  float* yb = (float*)(xl + XTE);
  size_t base = (size_t)(2*WRE + 2*XTE)*2;   // 18,546,688 bytes

  int nChunk = 1;
  if      (ws_size >= base + (size_t)8*128*YTOT*4) nChunk=8;
  else if (ws_size >= base + (size_t)4*128*YTOT*4) nChunk=4;
  else if (ws_size >= base + (size_t)2*128*YTOT*4) nChunk=2;

  prep_w<<<dim3(WRE/256), 256, 0, stream>>>(w, wh, wl);
  prep_x<<<dim3(XTE/256), 256, 0, stream>>>(x, xh, xl);

  for (int n0=0; n0<NBATCH; n0+=nChunk){
    stage1<0,0,0><<<dim3(5,17,nChunk),128,0,stream>>>(xh,xl,wh,wl,yb,n0);
    stage1<0,0,1><<<dim3(5,17,nChunk),128,0,stream>>>(xh,xl,wh,wl,yb,n0);
    stage1<0,1,0><<<dim3(5,17,nChunk),128,0,stream>>>(xh,xl,wh,wl,yb,n0);
    stage1<0,1,1><<<dim3(4,17,nChunk),128,0,stream>>>(xh,xl,wh,wl,yb,n0);
    stage1<1,0,0><<<dim3(5,16,nChunk),128,0,stream>>>(xh,xl,wh,wl,yb,n0);
    stage1<1,0,1><<<dim3(5,16,nChunk),128,0,stream>>>(xh,xl,wh,wl,yb,n0);
    stage1<1,1,0><<<dim3(5,16,nChunk),128,0,stream>>>(xh,xl,wh,wl,yb,n0);
    stage1<1,1,1><<<dim3(4,16,nChunk),128,0,stream>>>(xh,xl,wh,wl,yb,n0);
    stage2<<<dim3(8,128,nChunk),256,0,stream>>>(yb,bias,out,n0,0,128);
  }
}

// Round 4
// 613.579 us; speedup vs baseline: 4.0828x; 1.5226x over previous
//
#include <hip/hip_runtime.h>

typedef __attribute__((ext_vector_type(4))) float f32x4;
typedef __attribute__((ext_vector_type(8))) short s16x8;
typedef unsigned short u16;
typedef unsigned int   u32;

#define NBATCH 8
#define ICN 256
#define OCN 128
#define VOL 35937      // 33*33*33 dense upsampled volume per (n,oc)
#define PLANE 1089     // 33*33
#define WRE 884736     // 27*8*8*512 = 27*256*128
#define XTE 8388608    // 8*256*4096

__device__ __forceinline__ u16 f2bf(float v){
  u32 u = __float_as_uint(v);
  u32 r = u + 0x7FFFu + ((u>>16)&1u);
  return (u16)(r>>16);
}
__device__ __forceinline__ float bf2f(u16 b){ return __uint_as_float(((u32)b)<<16); }

// ---- prep_w2: w[oc][ic][27] fp32 -> w2[tap27][icc8][og8][lane64][e8] bf16 hi/lo ----
// B-fragment for MFMA: lane ln supplies oc = og*16+(ln&15), ic-octet (ln>>4).
__global__ __launch_bounds__(256) void prep_w2(const float* __restrict__ w,
                                               u16* __restrict__ wh, u16* __restrict__ wl){
  int idx = blockIdx.x*256 + threadIdx.x;   // WRE exactly
  int e = idx&7, ln=(idx>>3)&63, og=(idx>>9)&7, icc=(idx>>12)&7, tt=idx>>15;
  int oc = og*16 + (ln&15);
  int ic = icc*32 + ((ln>>4)&3)*8 + e;
  const int toffs[8] = {0,8,12,16,18,22,24,26};
  const int tcnt[8]  = {8,4,4,2,4,2,2,1};
  int c=0, t=0;
  #pragma unroll
  for (int cc=0; cc<8; ++cc)
    if (tt>=toffs[cc] && tt<toffs[cc]+tcnt[cc]){ c=cc; t=tt-toffs[cc]; }
  int ez=c>>2, ey=(c>>1)&1, ex=c&1;
  int ty=2-ey, tx=2-ex;
  int ax=t%tx, ay=(t/tx)%ty, az=t/(tx*ty);
  int qz = ez?1:(az?2:0), qy = ey?1:(ay?2:0), qx = ex?1:(ax?2:0);
  float v = w[((size_t)oc*ICN + ic)*27 + (qz*3+qy)*3+qx];
  u16 h = f2bf(v);
  wh[idx] = h;
  wl[idx] = f2bf(v - bf2f(h));
}

// ---- prep_x: x[n][ic][4096] fp32 -> x2[n][icc8][4096 pos][32 ic] bf16 hi/lo ----
__global__ __launch_bounds__(256) void prep_x(const float* __restrict__ x,
                                              u16* __restrict__ xh, u16* __restrict__ xl){
  u32 o = blockIdx.x*256 + threadIdx.x;   // XTE exactly
  int il = o & 31, p = (o>>5)&4095, icc = (o>>17)&7, n = o>>20;
  float v = x[(size_t)(n*256 + icc*32 + il)*4096 + p];
  u16 h = f2bf(v);
  xh[o] = h;
  xl[o] = f2bf(v - bf2f(h));
}

// ---- stage 1: per-class dense conv via split-bf16 MFMA; B-frags from L2 ----
// block 128 (2 waves), wave tile 64m x 128oc; grid (ceil(NXY/128), DZ, nChunk)
template<int EZ,int EY,int EX>
__global__ __launch_bounds__(128) void stage1(const u16* __restrict__ xh, const u16* __restrict__ xl,
                                              const u16* __restrict__ wh, const u16* __restrict__ wl,
                                              float* __restrict__ yd, int n0)
{
  constexpr int TZ=2-EZ, TY=2-EY, TX=2-EX;
  constexpr int DX=17-EX, DY=17-EY;
  constexpr int NXY=DY*DX;
  constexpr int CLS = EZ*4+EY*2+EX;
  constexpr int W27 = (CLS==0)?0:(CLS==1)?8:(CLS==2)?12:(CLS==3)?16:
                      (CLS==4)?18:(CLS==5)?22:(CLS==6)?24:26;
  constexpr int AST  = 40;             // u16 per position (32 ic + 8 pad) -> 80 B, 16B-aligned
  constexpr int APOS = TZ*10*17;
  constexpr int AHALF= APOS*AST;       // u16
  constexpr int ABYTES = 2*AHALF*2;    // hi+lo
  constexpr int TRBYTES = 2*128*33*4;  // 2 waves x [128 oc][33 m] f32
  constexpr int POOLB = (ABYTES > TRBYTES) ? ABYTES : TRBYTES;
  __shared__ __align__(16) char pool[POOLB];
  u16* As = (u16*)pool;

  const int tid=threadIdx.x, wv=tid>>6, ln=tid&63;
  const int mt=blockIdx.x, mz=blockIdx.y, nl=blockIdx.z;
  const int my0=(mt*128)/DX;

  int posA[4];
  #pragma unroll
  for (int fi=0; fi<4; ++fi){
    int m = mt*128 + wv*64 + fi*16 + (ln&15);
    if (m > NXY-1) m = NXY-1;          // clamp (stores guarded)
    int my=m/DX, mx=m-my*DX;
    posA[fi] = ((my-my0)*17 + mx)*AST + (ln>>4)*8;
  }

  f32x4 acc[4][8];
  #pragma unroll
  for (int i=0;i<4;++i)
    #pragma unroll
    for (int j=0;j<8;++j) acc[i][j]=(f32x4){0.f,0.f,0.f,0.f};

  const size_t nbase = (size_t)(n0+nl)*(ICN*4096);

  #pragma unroll 1
  for (int icc=0; icc<8; ++icc){
    // stage A tile (hi+lo): TZ z x 10 rows x 17 x, 32 ic each
    #pragma unroll 1
    for (int s=tid; s<APOS*4; s+=128){
      int icg=s&3, pos=s>>2;
      int xi = pos%17;
      int rem = pos/17;
      int yi = rem%10, az = rem/10;
      int zc = EZ ? mz : (mz-1+az);
      int yc = my0 + yi + (EY-1);
      int xc = xi + (EX-1);
      uint4 vh={0,0,0,0}, vlo={0,0,0,0};
      if ((u32)zc<16u && (u32)yc<16u && (u32)xc<16u){
        size_t g = nbase + (size_t)icc*131072 + (size_t)((zc*256+yc*16+xc)*32 + icg*8);
        vh  = *(const uint4*)(xh+g);
        vlo = *(const uint4*)(xl+g);
      }
      *(uint4*)&As[pos*AST + icg*8]         = vh;
      *(uint4*)&As[AHALF + pos*AST + icg*8] = vlo;
    }
    __syncthreads();

    #pragma unroll
    for (int az=0; az<TZ; ++az)
    #pragma unroll
    for (int ay=0; ay<TY; ++ay)
    #pragma unroll
    for (int ax=0; ax<TX; ++ax){
      const int t = (az*TY+ay)*TX+ax;
      const int toff = ((az*10+ay)*17+ax)*AST;
      s16x8 ah[4], al[4];
      #pragma unroll
      for (int fi=0; fi<4; ++fi){
        ah[fi] = *(const s16x8*)&As[posA[fi]+toff];
        al[fi] = *(const s16x8*)&As[AHALF+posA[fi]+toff];
      }
      const u16* bph = wh + (size_t)(((W27+t)*8+icc)*8)*512 + ln*8;
      const u16* bpl = wl + (size_t)(((W27+t)*8+icc)*8)*512 + ln*8;
      s16x8 bh[8];
      #pragma unroll
      for (int og=0; og<8; ++og) bh[og] = *(const s16x8*)(bph + og*512);
      #pragma unroll
      for (int fi=0; fi<4; ++fi)
        #pragma unroll
        for (int og=0; og<8; ++og){
          acc[fi][og] = __builtin_amdgcn_mfma_f32_16x16x32_bf16(ah[fi], bh[og], acc[fi][og],0,0,0);
          acc[fi][og] = __builtin_amdgcn_mfma_f32_16x16x32_bf16(al[fi], bh[og], acc[fi][og],0,0,0);
        }
      s16x8 bl[8];
      #pragma unroll
      for (int og=0; og<8; ++og) bl[og] = *(const s16x8*)(bpl + og*512);
      #pragma unroll
      for (int fi=0; fi<4; ++fi)
        #pragma unroll
        for (int og=0; og<8; ++og)
          acc[fi][og] = __builtin_amdgcn_mfma_f32_16x16x32_bf16(ah[fi], bl[og], acc[fi][og],0,0,0);
    }
    __syncthreads();
  }

  // epilogue: per-wave transpose (2 half-passes of 32 m), dense stride-2 store
  float* tr = (float*)pool + wv*(128*33);
  const size_t ybn = (size_t)(nl*128)*VOL;
  #pragma unroll
  for (int pass=0; pass<2; ++pass){
    #pragma unroll
    for (int fi=0; fi<2; ++fi)
      #pragma unroll
      for (int og=0; og<8; ++og)
        #pragma unroll
        for (int j=0; j<4; ++j)
          tr[(og*16+(ln&15))*33 + fi*16 + (ln>>4)*4 + j] = acc[pass*2+fi][og][j];
    int m = mt*128 + wv*64 + pass*32 + (ln&31);
    bool valid = m < NXY;
    int mm = valid ? m : 0;
    int my=mm/DX, mx=mm-my*DX;
    int uz=2*mz+EZ, uy=2*my+EY, ux=2*mx+EX;
    size_t soff = (size_t)uz*PLANE + (size_t)uy*33 + ux;
    #pragma unroll 4
    for (int i=0; i<64; ++i){
      int oc = 2*i + (ln>>5);
      float v = tr[oc*33 + (ln&31)];
      if (valid) yd[ybn + (size_t)oc*VOL + soff] = v;
    }
  }
}

// ---- stage 2: dense separable FIR ([.25 .75 .75 .25] per axis) + bias ----
// grid (2 zg, 128 oc, nChunk), block 256; streams 19 uz planes -> 16 oz planes
__global__ __launch_bounds__(256) void stage2d(const float* __restrict__ yd, const float* __restrict__ bias,
                                               float* __restrict__ out, int n0){
  __shared__ float raw[33][36];
  __shared__ float fx[35][36];
  const int tid=threadIdx.x;
  const int zg=blockIdx.x, oc=blockIdx.y, nl=blockIdx.z;
  const float* yb = yd + (size_t)(nl*128+oc)*VOL;
  const float b = bias[oc];
  float* ob = out + (size_t)((n0+nl)*128+oc)*32768;
  if (tid < 72){ fx[(tid>=36)?34:0][tid%36] = 0.f; }
  float a0[4]={0,0,0,0}, a1[4]={0,0,0,0}, a2[4]={0,0,0,0};
  #pragma unroll 1
  for (int s=0; s<19; ++s){
    int uz = zg*16 - 1 + s;
    for (int t2=tid; t2<1188; t2+=256){
      int uy = t2/36, uxm = t2 - uy*36, ux = uxm-1;
      float v = 0.f;
      if ((u32)uz<33u && (u32)ux<33u) v = yb[(size_t)uz*PLANE + uy*33 + ux];
      raw[uy][uxm] = v;
    }
    __syncthreads();
    for (int t2=tid; t2<1056; t2+=256){
      int uy = t2>>5, ox = t2&31;
      fx[uy+1][ox] = 0.25f*raw[uy][ox] + 0.75f*raw[uy][ox+1]
                   + 0.75f*raw[uy][ox+2] + 0.25f*raw[uy][ox+3];
    }
    __syncthreads();
    #pragma unroll
    for (int k=0;k<4;++k){
      int pos = tid + k*256;
      int oy = pos>>5, ox = pos&31;
      float fv = 0.25f*fx[oy][ox] + 0.75f*fx[oy+1][ox]
               + 0.75f*fx[oy+2][ox] + 0.25f*fx[oy+3][ox];
      if (s >= 3){
        int oz = zg*16 + s - 3;
        ob[(size_t)oz*1024 + pos] = a0[k] + 0.25f*fv + b;
      }
      a0[k] = a1[k] + 0.75f*fv;
      a1[k] = a2[k] + 0.75f*fv;
      a2[k] = 0.25f*fv;
    }
    __syncthreads();
  }
}

extern "C" void kernel_launch(void* const* d_in, const int* in_sizes, int n_in,
                              void* d_out, int out_size, void* d_ws, size_t ws_size,
                              hipStream_t stream) {
  const float* x    = (const float*)d_in[0];
  const float* w    = (const float*)d_in[1];
  const float* bias = (const float*)d_in[2];
  float* out = (float*)d_out;

  u16* wh = (u16*)d_ws;
  u16* wl = wh + WRE;
  u16* xh = wl + WRE;
  u16* xl = xh + XTE;
  float* yd = (float*)(xl + XTE);
  size_t base = (size_t)(2*WRE + 2*XTE)*2;

  int nChunk = 1;
  if      (ws_size >= base + (size_t)8*128*VOL*4) nChunk=8;
  else if (ws_size >= base + (size_t)4*128*VOL*4) nChunk=4;
  else if (ws_size >= base + (size_t)2*128*VOL*4) nChunk=2;

  prep_w2<<<dim3(WRE/256), 256, 0, stream>>>(w, wh, wl);
  prep_x<<<dim3(XTE/256), 256, 0, stream>>>(x, xh, xl);

  for (int n0=0; n0<NBATCH; n0+=nChunk){
    stage1<0,0,0><<<dim3(3,17,nChunk),128,0,stream>>>(xh,xl,wh,wl,yd,n0);
    stage1<0,0,1><<<dim3(3,17,nChunk),128,0,stream>>>(xh,xl,wh,wl,yd,n0);
    stage1<0,1,0><<<dim3(3,17,nChunk),128,0,stream>>>(xh,xl,wh,wl,yd,n0);
    stage1<0,1,1><<<dim3(2,17,nChunk),128,0,stream>>>(xh,xl,wh,wl,yd,n0);
    stage1<1,0,0><<<dim3(3,16,nChunk),128,0,stream>>>(xh,xl,wh,wl,yd,n0);
    stage1<1,0,1><<<dim3(3,16,nChunk),128,0,stream>>>(xh,xl,wh,wl,yd,n0);
    stage1<1,1,0><<<dim3(3,16,nChunk),128,0,stream>>>(xh,xl,wh,wl,yd,n0);
    stage1<1,1,1><<<dim3(2,16,nChunk),128,0,stream>>>(xh,xl,wh,wl,yd,n0);
    stage2d<<<dim3(2,128,nChunk),256,0,stream>>>(yd,bias,out,n0);
  }
}

// Round 5
// 467.980 us; speedup vs baseline: 5.3530x; 1.3111x over previous
//
#include <hip/hip_runtime.h>

typedef __attribute__((ext_vector_type(4))) float f32x4;
typedef __attribute__((ext_vector_type(8))) short s16x8;
typedef unsigned short u16;
typedef unsigned int   u32;

#define NBATCH 8
#define ICN 256
#define OCN 128
#define VOL 35937      // 33*33*33 dense upsampled volume per (n,oc)
#define PLANE 1089     // 33*33
#define WRE 884736     // 27*8*8*512 = 27*256*128
#define XTE 8388608    // 8*256*4096
#define S1POOL 33792   // max(per-plane A = 27200, transpose = 2*128*33*4 = 33792)

__device__ __forceinline__ u16 f2bf(float v){
  u32 u = __float_as_uint(v);
  u32 r = u + 0x7FFFu + ((u>>16)&1u);
  return (u16)(r>>16);
}
__device__ __forceinline__ float bf2f(u16 b){ return __uint_as_float(((u32)b)<<16); }

// ---- prep_w2: w[oc][ic][27] fp32 -> w2[tap27][icc8][og8][lane64][e8] bf16 hi/lo ----
__global__ __launch_bounds__(256) void prep_w2(const float* __restrict__ w,
                                               u16* __restrict__ wh, u16* __restrict__ wl){
  int idx = blockIdx.x*256 + threadIdx.x;   // WRE exactly
  int e = idx&7, ln=(idx>>3)&63, og=(idx>>9)&7, icc=(idx>>12)&7, tt=idx>>15;
  int oc = og*16 + (ln&15);
  int ic = icc*32 + ((ln>>4)&3)*8 + e;
  const int toffs[8] = {0,8,12,16,18,22,24,26};
  const int tcnt[8]  = {8,4,4,2,4,2,2,1};
  int c=0, t=0;
  #pragma unroll
  for (int cc=0; cc<8; ++cc)
    if (tt>=toffs[cc] && tt<toffs[cc]+tcnt[cc]){ c=cc; t=tt-toffs[cc]; }
  int ez=c>>2, ey=(c>>1)&1, ex=c&1;
  int ty=2-ey, tx=2-ex;
  int ax=t%tx, ay=(t/tx)%ty, az=t/(tx*ty);
  int qz = ez?1:(az?2:0), qy = ey?1:(ay?2:0), qx = ex?1:(ax?2:0);
  float v = w[((size_t)oc*ICN + ic)*27 + (qz*3+qy)*3+qx];
  u16 h = f2bf(v);
  wh[idx] = h;
  wl[idx] = f2bf(v - bf2f(h));
}

// ---- prep_x: x[n][ic][4096] fp32 -> x2[n][icc8][4096 pos][32 ic] bf16 hi/lo ----
__global__ __launch_bounds__(256) void prep_x(const float* __restrict__ x,
                                              u16* __restrict__ xh, u16* __restrict__ xl){
  u32 o = blockIdx.x*256 + threadIdx.x;   // XTE exactly
  int il = o & 31, p = (o>>5)&4095, icc = (o>>17)&7, n = o>>20;
  float v = x[(size_t)(n*256 + icc*32 + il)*4096 + p];
  u16 h = f2bf(v);
  xh[o] = h;
  xl[o] = f2bf(v - bf2f(h));
}

// ---- stage 1 body: per-class dense conv via split-bf16 MFMA; B-frags from L2 ----
// block 128 (2 waves), wave tile 64m x 128oc; A staged one z-plane at a time
template<int EZ,int EY,int EX>
__device__ __forceinline__ void s1body(char* pool,
                                       const u16* __restrict__ xh, const u16* __restrict__ xl,
                                       const u16* __restrict__ wh, const u16* __restrict__ wl,
                                       float* __restrict__ yd, int n0, int rem, int nl, int tid)
{
  constexpr int TZ=2-EZ, TY=2-EY, TX=2-EX;
  constexpr int DX=17-EX, DY=17-EY;
  constexpr int NXY=DY*DX;
  constexpr int MT=(NXY+127)/128;
  constexpr int CLS = EZ*4+EY*2+EX;
  constexpr int W27 = (CLS==0)?0:(CLS==1)?8:(CLS==2)?12:(CLS==3)?16:
                      (CLS==4)?18:(CLS==5)?22:(CLS==6)?24:26;
  constexpr int AST   = 40;        // u16 per position (32 ic + 8 pad) -> 80 B
  constexpr int APOSP = 170;       // 10 rows x 17 x per plane
  constexpr int AHALFP= APOSP*AST; // u16 per half
  u16* As = (u16*)pool;

  const int wv=tid>>6, ln=tid&63;
  const int mt = rem % MT, mz = rem / MT;
  const int my0=(mt*128)/DX;

  int posA[4];
  #pragma unroll
  for (int fi=0; fi<4; ++fi){
    int m = mt*128 + wv*64 + fi*16 + (ln&15);
    if (m > NXY-1) m = NXY-1;      // clamp (stores guarded)
    int my=m/DX, mx=m-my*DX;
    posA[fi] = ((my-my0)*17 + mx)*AST + (ln>>4)*8;
  }

  f32x4 acc[4][8];
  #pragma unroll
  for (int i=0;i<4;++i)
    #pragma unroll
    for (int j=0;j<8;++j) acc[i][j]=(f32x4){0.f,0.f,0.f,0.f};

  const size_t nbase = (size_t)(n0+nl)*(ICN*4096);

  #pragma unroll 1
  for (int icc=0; icc<8; ++icc){
    #pragma unroll
    for (int az=0; az<TZ; ++az){
      // stage one z-plane (hi+lo): 10 rows x 17 x, 32 ic each
      #pragma unroll 1
      for (int s=tid; s<APOSP*4; s+=128){
        int icg=s&3, pos=s>>2;
        int xi = pos%17, yi = pos/17;
        int zc = EZ ? mz : (mz-1+az);
        int yc = my0 + yi + (EY-1);
        int xc = xi + (EX-1);
        uint4 vh={0,0,0,0}, vlo={0,0,0,0};
        if ((u32)zc<16u && (u32)yc<16u && (u32)xc<16u){
          size_t g = nbase + (size_t)icc*131072 + (size_t)((zc*256+yc*16+xc)*32 + icg*8);
          vh  = *(const uint4*)(xh+g);
          vlo = *(const uint4*)(xl+g);
        }
        *(uint4*)&As[pos*AST + icg*8]          = vh;
        *(uint4*)&As[AHALFP + pos*AST + icg*8] = vlo;
      }
      __syncthreads();

      #pragma unroll
      for (int ay=0; ay<TY; ++ay)
      #pragma unroll
      for (int ax=0; ax<TX; ++ax){
        const int t = (az*TY+ay)*TX+ax;
        const int toff = (ay*17+ax)*AST;
        s16x8 ah[4], al[4];
        #pragma unroll
        for (int fi=0; fi<4; ++fi){
          ah[fi] = *(const s16x8*)&As[posA[fi]+toff];
          al[fi] = *(const s16x8*)&As[AHALFP+posA[fi]+toff];
        }
        const u16* bph = wh + (size_t)(((W27+t)*8+icc)*8)*512 + ln*8;
        const u16* bpl = wl + (size_t)(((W27+t)*8+icc)*8)*512 + ln*8;
        s16x8 bh[8];
        #pragma unroll
        for (int og=0; og<8; ++og) bh[og] = *(const s16x8*)(bph + og*512);
        #pragma unroll
        for (int fi=0; fi<4; ++fi)
          #pragma unroll
          for (int og=0; og<8; ++og){
            acc[fi][og] = __builtin_amdgcn_mfma_f32_16x16x32_bf16(ah[fi], bh[og], acc[fi][og],0,0,0);
            acc[fi][og] = __builtin_amdgcn_mfma_f32_16x16x32_bf16(al[fi], bh[og], acc[fi][og],0,0,0);
          }
        s16x8 bl[8];
        #pragma unroll
        for (int og=0; og<8; ++og) bl[og] = *(const s16x8*)(bpl + og*512);
        #pragma unroll
        for (int fi=0; fi<4; ++fi)
          #pragma unroll
          for (int og=0; og<8; ++og)
            acc[fi][og] = __builtin_amdgcn_mfma_f32_16x16x32_bf16(ah[fi], bl[og], acc[fi][og],0,0,0);
      }
      __syncthreads();
    }
  }

  // epilogue: per-wave transpose (2 half-passes of 32 m), dense stride-2 store
  float* tr = (float*)pool + wv*(128*33);
  const size_t ybn = (size_t)(nl*128)*VOL;
  #pragma unroll
  for (int pass=0; pass<2; ++pass){
    #pragma unroll
    for (int fi=0; fi<2; ++fi)
      #pragma unroll
      for (int og=0; og<8; ++og)
        #pragma unroll
        for (int j=0; j<4; ++j)
          tr[(og*16+(ln&15))*33 + fi*16 + (ln>>4)*4 + j] = acc[pass*2+fi][og][j];
    int m = mt*128 + wv*64 + pass*32 + (ln&31);
    bool valid = m < NXY;
    int mm = valid ? m : 0;
    int my=mm/DX, mx=mm-my*DX;
    int uz=2*mz+EZ, uy=2*my+EY, ux=2*mx+EX;
    size_t soff = (size_t)uz*PLANE + (size_t)uy*33 + ux;
    #pragma unroll 4
    for (int i=0; i<64; ++i){
      int oc = 2*i + (ln>>5);
      float v = tr[oc*33 + (ln&31)];
      if (valid) yd[ybn + (size_t)oc*VOL + soff] = v;
    }
  }
}

// ---- fused stage 1: all 8 parity classes in one dispatch ----
// blockIdx.x in [0,363): class-tile id; blockIdx.z = n within chunk
__global__ __launch_bounds__(128) void stage1f(const u16* __restrict__ xh, const u16* __restrict__ xl,
                                               const u16* __restrict__ wh, const u16* __restrict__ wl,
                                               float* __restrict__ yd, int n0){
  __shared__ __align__(16) char pool[S1POOL];
  const int bz = blockIdx.x, nl = blockIdx.z, tid = threadIdx.x;
  if      (bz <  51) s1body<0,0,0>(pool,xh,xl,wh,wl,yd,n0,bz    ,nl,tid);
  else if (bz < 102) s1body<0,0,1>(pool,xh,xl,wh,wl,yd,n0,bz- 51,nl,tid);
  else if (bz < 153) s1body<0,1,0>(pool,xh,xl,wh,wl,yd,n0,bz-102,nl,tid);
  else if (bz < 187) s1body<0,1,1>(pool,xh,xl,wh,wl,yd,n0,bz-153,nl,tid);
  else if (bz < 235) s1body<1,0,0>(pool,xh,xl,wh,wl,yd,n0,bz-187,nl,tid);
  else if (bz < 283) s1body<1,0,1>(pool,xh,xl,wh,wl,yd,n0,bz-235,nl,tid);
  else if (bz < 331) s1body<1,1,0>(pool,xh,xl,wh,wl,yd,n0,bz-283,nl,tid);
  else               s1body<1,1,1>(pool,xh,xl,wh,wl,yd,n0,bz-331,nl,tid);
}

// ---- stage 2: dense separable FIR ([.25 .75 .75 .25] per axis) + bias ----
__global__ __launch_bounds__(256) void stage2d(const float* __restrict__ yd, const float* __restrict__ bias,
                                               float* __restrict__ out, int n0){
  __shared__ float raw[33][36];
  __shared__ float fx[35][36];
  const int tid=threadIdx.x;
  const int zg=blockIdx.x, oc=blockIdx.y, nl=blockIdx.z;
  const float* yb = yd + (size_t)(nl*128+oc)*VOL;
  const float b = bias[oc];
  float* ob = out + (size_t)((n0+nl)*128+oc)*32768;
  if (tid < 72){ fx[(tid>=36)?34:0][tid%36] = 0.f; }
  float a0[4]={0,0,0,0}, a1[4]={0,0,0,0}, a2[4]={0,0,0,0};
  #pragma unroll 1
  for (int s=0; s<19; ++s){
    int uz = zg*16 - 1 + s;
    for (int t2=tid; t2<1188; t2+=256){
      int uy = t2/36, uxm = t2 - uy*36, ux = uxm-1;
      float v = 0.f;
      if ((u32)uz<33u && (u32)ux<33u) v = yb[(size_t)uz*PLANE + uy*33 + ux];
      raw[uy][uxm] = v;
    }
    __syncthreads();
    for (int t2=tid; t2<1056; t2+=256){
      int uy = t2>>5, ox = t2&31;
      fx[uy+1][ox] = 0.25f*raw[uy][ox] + 0.75f*raw[uy][ox+1]
                   + 0.75f*raw[uy][ox+2] + 0.25f*raw[uy][ox+3];
    }
    __syncthreads();
    #pragma unroll
    for (int k=0;k<4;++k){
      int pos = tid + k*256;
      int oy = pos>>5, ox = pos&31;
      float fv = 0.25f*fx[oy][ox] + 0.75f*fx[oy+1][ox]
               + 0.75f*fx[oy+2][ox] + 0.25f*fx[oy+3][ox];
      if (s >= 3){
        int oz = zg*16 + s - 3;
        ob[(size_t)oz*1024 + pos] = a0[k] + 0.25f*fv + b;
      }
      a0[k] = a1[k] + 0.75f*fv;
      a1[k] = a2[k] + 0.75f*fv;
      a2[k] = 0.25f*fv;
    }
    __syncthreads();
  }
}

extern "C" void kernel_launch(void* const* d_in, const int* in_sizes, int n_in,
                              void* d_out, int out_size, void* d_ws, size_t ws_size,
                              hipStream_t stream) {
  const float* x    = (const float*)d_in[0];
  const float* w    = (const float*)d_in[1];
  const float* bias = (const float*)d_in[2];
  float* out = (float*)d_out;

  u16* wh = (u16*)d_ws;
  u16* wl = wh + WRE;
  u16* xh = wl + WRE;
  u16* xl = xh + XTE;
  float* yd = (float*)(xl + XTE);
  size_t base = (size_t)(2*WRE + 2*XTE)*2;

  int nChunk = 1;
  if      (ws_size >= base + (size_t)8*128*VOL*4) nChunk=8;
  else if (ws_size >= base + (size_t)4*128*VOL*4) nChunk=4;
  else if (ws_size >= base + (size_t)2*128*VOL*4) nChunk=2;

  prep_w2<<<dim3(WRE/256), 256, 0, stream>>>(w, wh, wl);
  prep_x<<<dim3(XTE/256), 256, 0, stream>>>(x, xh, xl);

  for (int n0=0; n0<NBATCH; n0+=nChunk){
    stage1f<<<dim3(363,1,nChunk),128,0,stream>>>(xh,xl,wh,wl,yd,n0);
    stage2d<<<dim3(2,128,nChunk),256,0,stream>>>(yd,bias,out,n0);
  }
}